// Round 1
// baseline (688.709 us; speedup 1.0000x reference)
//
#include <hip/hip_runtime.h>

typedef __bf16 bf16_t;
typedef __bf16 bf16x8 __attribute__((ext_vector_type(8)));
typedef float  f32x4  __attribute__((ext_vector_type(4)));

// XOR-swizzled LDS index for a [64][256] bf16 tile: 16B-granule index XORed with
// (row&7) so that A-fragment column reads (16 lanes, 512B row stride) spread over
// all 32 banks (2-way max = free).
__device__ __forceinline__ int swz(int row, int col) {
    return row * 256 + ((((col >> 3) ^ (row & 7)) << 3) | (col & 7));
}

// ---------------------------------------------------------------------------
// BN stats (training mode): mean + rsqrt(var+eps) per feature over M rows.
// stats layout: [mu(D), rstd(D)]
__global__ void bn_stats_kernel(const float* __restrict__ x, int M, int D,
                                float* __restrict__ stats) {
    __shared__ float s1[256], s2[256];
    int tid = threadIdx.x;
    float a = 0.f, b = 0.f;
    int N = M * D;
    for (int idx = tid; idx < N; idx += 256) {  // stride 256 keeps col = tid % D fixed
        float v = x[idx];
        a += v; b += v * v;
    }
    s1[tid] = a; s2[tid] = b;
    __syncthreads();
    if (tid < D) {
        float sa = 0.f, sb = 0.f;
        for (int k = tid; k < 256; k += D) { sa += s1[k]; sb += s2[k]; }
        float mu  = sa / (float)M;
        float var = sb / (float)M - mu * mu;
        stats[tid]     = mu;
        stats[D + tid] = rsqrtf(var + 1e-5f);
    }
}

// Normalize + K-pad to 32 cols, bf16 output. Xn[m][dp<32]
__global__ void normalize_kernel(const float* __restrict__ x, const float* __restrict__ stats,
                                 bf16_t* __restrict__ Xn, int M, int D) {
    int idx = blockIdx.x * 256 + threadIdx.x;
    if (idx >= M * 32) return;
    int m = idx >> 5, dp = idx & 31;
    float v = 0.f;
    if (dp < D) v = (x[m * D + dp] - stats[dp]) * stats[D + dp];
    Xn[idx] = (bf16_t)v;
}

// Fold gamma into W1 (transposed to [j][h][32], K-padded, bf16) and beta into b1:
// b1p[j][h] = b1[j][h] + sum_d beta[j][d] * W1[j][d][h]
__global__ __launch_bounds__(256) void prep_w1_kernel(
    const float* __restrict__ W1, const float* __restrict__ b1,
    const float* __restrict__ gamma, const float* __restrict__ beta,
    bf16_t* __restrict__ W1t, float* __restrict__ b1p, int D) {
    int j = blockIdx.x, h = threadIdx.x;
    float bacc = b1[j * 256 + h];
    bf16_t* orow = W1t + (size_t)(j * 256 + h) * 32;
    for (int d = 0; d < 32; d++) orow[d] = (bf16_t)0.f;
    for (int d = 0; d < D; d++) {
        float w = W1[((size_t)j * D + d) * 256 + h];
        orow[d] = (bf16_t)(gamma[j * D + d] * w);
        bacc += beta[j * D + d] * w;
    }
    b1p[j * 256 + h] = bacc;
}

// Batched transpose fp32 [B][R][C] -> bf16 [B][C][R], optional per-(b,c) scale fold.
__global__ __launch_bounds__(256) void transpose_kernel(
    const float* __restrict__ in, bf16_t* __restrict__ outp,
    const float* __restrict__ scale, int R, int C) {
    __shared__ float tile[32][33];
    int b = blockIdx.z;
    int r0 = blockIdx.y * 32, c0 = blockIdx.x * 32;
    int tx = threadIdx.x & 31, ty = threadIdx.x >> 5;
    const float* ip = in + (size_t)b * R * C;
    #pragma unroll
    for (int i = 0; i < 4; i++)
        tile[ty + i * 8][tx] = ip[(size_t)(r0 + ty + i * 8) * C + c0 + tx];
    __syncthreads();
    bf16_t* op = outp + (size_t)b * R * C;
    #pragma unroll
    for (int i = 0; i < 4; i++) {
        int c = c0 + ty + i * 8;
        float sc = scale ? scale[b * C + c] : 1.f;
        op[(size_t)c * R + r0 + tx] = (bf16_t)(tile[tx][ty + i * 8] * sc);
    }
}

// ---------------------------------------------------------------------------
// Fused 3-layer MLP for one (net j, 64-row tile). bf16 MFMA 16x16x32.
// A-frag: A[m=lane&15][k=quad*8+jj]; B-frag: Bt rows [n=lane&15][k] (weights
// stored transposed); C/D: col=lane&15, row=quad*4+reg.
__global__ __launch_bounds__(256) void fused_mlp_kernel(
    const bf16_t* __restrict__ Xn,                                   // [M][32]
    const bf16_t* __restrict__ W1t, const float* __restrict__ b1p,   // [j][256][32], [j][256]
    const bf16_t* __restrict__ W2t, const float* __restrict__ b2,    // [j][256][256], [j][256]
    const bf16_t* __restrict__ W3t,                                  // [j][128][256] (scale folded)
    bf16_t* __restrict__ outp, int M)                                // [j][M][128]
{
    const int j    = blockIdx.y;
    const int row0 = blockIdx.x * 64;
    const int tid  = threadIdx.x;
    const int wave = tid >> 6;
    const int lane = tid & 63;
    const int quad = lane >> 4;
    const int l16  = lane & 15;

    __shared__ __align__(16) bf16_t h1s[64 * 256];   // 32 KB
    __shared__ __align__(16) bf16_t h2s[64 * 256];   // 32 KB

    const f32x4 vzero = {0.f, 0.f, 0.f, 0.f};

    // ---------------- layer 1 (K=32, zero-padded) ----------------
    {
        f32x4 acc[4][4];
        #pragma unroll
        for (int a = 0; a < 4; a++)
            #pragma unroll
            for (int c = 0; c < 4; c++) acc[a][c] = vzero;

        bf16x8 afr[4];
        #pragma unroll
        for (int mb = 0; mb < 4; mb++)
            afr[mb] = *reinterpret_cast<const bf16x8*>(
                Xn + (size_t)(row0 + mb * 16 + l16) * 32 + quad * 8);

        #pragma unroll
        for (int nbi = 0; nbi < 4; nbi++) {
            const int n = (wave * 4 + nbi) * 16 + l16;
            bf16x8 bfr = *reinterpret_cast<const bf16x8*>(
                W1t + (size_t)(j * 256 + n) * 32 + quad * 8);
            #pragma unroll
            for (int mb = 0; mb < 4; mb++)
                acc[mb][nbi] = __builtin_amdgcn_mfma_f32_16x16x32_bf16(
                    afr[mb], bfr, acc[mb][nbi], 0, 0, 0);
        }
        #pragma unroll
        for (int nbi = 0; nbi < 4; nbi++) {
            const int n = (wave * 4 + nbi) * 16 + l16;
            const float bias = b1p[j * 256 + n];
            #pragma unroll
            for (int mb = 0; mb < 4; mb++)
                #pragma unroll
                for (int r = 0; r < 4; r++) {
                    float v = acc[mb][nbi][r] + bias;
                    v = v > 0.f ? v : 0.01f * v;
                    h1s[swz(mb * 16 + quad * 4 + r, n)] = (bf16_t)v;
                }
        }
    }
    __syncthreads();

    // ---------------- layer 2 (256x256) ----------------
    {
        f32x4 acc[4][4];
        #pragma unroll
        for (int a = 0; a < 4; a++)
            #pragma unroll
            for (int c = 0; c < 4; c++) acc[a][c] = vzero;

        #pragma unroll
        for (int kk = 0; kk < 8; kk++) {
            bf16x8 av[4];
            #pragma unroll
            for (int mb = 0; mb < 4; mb++) {
                const int row = mb * 16 + l16;
                const int gi  = (kk * 4 + quad) ^ (row & 7);
                av[mb] = *reinterpret_cast<const bf16x8*>(h1s + row * 256 + gi * 8);
            }
            #pragma unroll
            for (int nbi = 0; nbi < 4; nbi++) {
                const int n = (wave * 4 + nbi) * 16 + l16;
                bf16x8 bv = *reinterpret_cast<const bf16x8*>(
                    W2t + (size_t)(j * 256 + n) * 256 + kk * 32 + quad * 8);
                #pragma unroll
                for (int mb = 0; mb < 4; mb++)
                    acc[mb][nbi] = __builtin_amdgcn_mfma_f32_16x16x32_bf16(
                        av[mb], bv, acc[mb][nbi], 0, 0, 0);
            }
        }
        #pragma unroll
        for (int nbi = 0; nbi < 4; nbi++) {
            const int n = (wave * 4 + nbi) * 16 + l16;
            const float bias = b2[j * 256 + n];
            #pragma unroll
            for (int mb = 0; mb < 4; mb++)
                #pragma unroll
                for (int r = 0; r < 4; r++) {
                    float v = acc[mb][nbi][r] + bias;
                    v = v > 0.f ? v : 0.01f * v;
                    h2s[swz(mb * 16 + quad * 4 + r, n)] = (bf16_t)v;
                }
        }
    }
    __syncthreads();   // h2s ready; h1s free for reuse after this point

    // ---------------- layer 3 (256x128, no bias/act, scale folded) ----------------
    {
        f32x4 acc[4][2];
        #pragma unroll
        for (int a = 0; a < 4; a++) { acc[a][0] = vzero; acc[a][1] = vzero; }

        #pragma unroll
        for (int kk = 0; kk < 8; kk++) {
            bf16x8 av[4];
            #pragma unroll
            for (int mb = 0; mb < 4; mb++) {
                const int row = mb * 16 + l16;
                const int gi  = (kk * 4 + quad) ^ (row & 7);
                av[mb] = *reinterpret_cast<const bf16x8*>(h2s + row * 256 + gi * 8);
            }
            #pragma unroll
            for (int nbi = 0; nbi < 2; nbi++) {
                const int n = (wave * 2 + nbi) * 16 + l16;
                bf16x8 bv = *reinterpret_cast<const bf16x8*>(
                    W3t + (size_t)(j * 128 + n) * 256 + kk * 32 + quad * 8);
                #pragma unroll
                for (int mb = 0; mb < 4; mb++)
                    acc[mb][nbi] = __builtin_amdgcn_mfma_f32_16x16x32_bf16(
                        av[mb], bv, acc[mb][nbi], 0, 0, 0);
            }
        }
        // stage C-layout result into h1s (reused), then write coalesced
        #pragma unroll
        for (int nbi = 0; nbi < 2; nbi++) {
            const int n = (wave * 2 + nbi) * 16 + l16;
            #pragma unroll
            for (int mb = 0; mb < 4; mb++)
                #pragma unroll
                for (int r = 0; r < 4; r++)
                    h1s[swz(mb * 16 + quad * 4 + r, n)] = (bf16_t)acc[mb][nbi][r];
        }
    }
    __syncthreads();
    #pragma unroll
    for (int p = 0; p < 4; p++) {
        const int rr = p * 16 + (tid >> 4);
        const int c8 = (tid & 15) * 8;
        const int gi = (c8 >> 3) ^ (rr & 7);
        bf16x8 v = *reinterpret_cast<const bf16x8*>(h1s + rr * 256 + gi * 8);
        *reinterpret_cast<bf16x8*>(outp + ((size_t)j * M + row0 + rr) * 128 + c8) = v;
    }
}

// ---------------------------------------------------------------------------
// psi(0) per net: encoder of zeros. xn=0 -> layer1 preact = b1p. One block/net.
__global__ __launch_bounds__(256) void psi0_kernel(
    const float* __restrict__ b1p, const bf16_t* __restrict__ W2t,
    const float* __restrict__ b2, const bf16_t* __restrict__ W3t,
    float* __restrict__ psi0) {
    int j = blockIdx.x, tid = threadIdx.x;
    __shared__ float h1[256], h2[256];
    {
        float v = b1p[j * 256 + tid];
        h1[tid] = v > 0.f ? v : 0.01f * v;
    }
    __syncthreads();
    {
        float acc = b2[j * 256 + tid];
        const bf16_t* wrow = W2t + (size_t)(j * 256 + tid) * 256;
        for (int d = 0; d < 256; d++) acc += h1[d] * (float)wrow[d];
        h2[tid] = acc > 0.f ? acc : 0.01f * acc;
    }
    __syncthreads();
    if (tid < 128) {
        float acc = 0.f;
        const bf16_t* wrow = W3t + (size_t)(j * 128 + tid) * 256;
        for (int d = 0; d < 256; d++) acc += h2[d] * (float)wrow[d];
        psi0[j * 128 + tid] = acc;
    }
}

// y = (sum_j phi1s[:,1:]) @ C^T. One block per (ti, b), 128 threads.
__global__ __launch_bounds__(128) void y_kernel(
    const bf16_t* __restrict__ phi, const float* __restrict__ C_W,
    float* __restrict__ y) {
    int ti = blockIdx.x, b = blockIdx.y, l = threadIdx.x;
    __shared__ float S[128];
    const int m = b * 64 + ti + 1;
    float s = 0.f;
    for (int j = 0; j < 64; j++)
        s += (float)phi[((size_t)j * 4096 + m) * 128 + l];
    S[l] = s;
    __syncthreads();
    if (l < 16) {
        float acc = 0.f;
        for (int ll = 0; ll < 128; ll++) acc += S[ll] * C_W[l * 128 + ll];
        y[(b * 63 + ti) * 16 + l] = acc;
    }
}

// Koopman scan + j-sum + decode. One block per batch b; wave w holds nets
// j = w*8..w*8+7, lane = k (complex pair), state in regs.
__global__ __launch_bounds__(512) void recur_kernel(
    const bf16_t* __restrict__ phi, const bf16_t* __restrict__ psiu,
    const float* __restrict__ psi0, const float* __restrict__ reL,
    const float* __restrict__ imL, const float* __restrict__ C_W,
    float* __restrict__ ypred) {
    const int b = blockIdx.x;
    const int tid = threadIdx.x;
    const int wave = tid >> 6, lane = tid & 63;
    __shared__ float red[8][128];
    __shared__ float S[128];
    __shared__ float Cs[16 * 128];
    for (int i = tid; i < 2048; i += 512) Cs[i] = C_W[i];

    float sx[8], sy[8], p0x[8], p0y[8], lre[8], lim[8];
    #pragma unroll
    for (int i = 0; i < 8; i++) {
        const int j = wave * 8 + i;
        const bf16_t* pp = phi + ((size_t)j * 4096 + b * 64) * 128 + lane * 2;
        sx[i] = (float)pp[0];
        sy[i] = (float)pp[1];
        p0x[i] = psi0[j * 128 + lane * 2];
        p0y[i] = psi0[j * 128 + lane * 2 + 1];
        lre[i] = reL[j];
        lim[i] = imL[j];
    }
    __syncthreads();

    for (int t = 0; t < 63; t++) {
        float lsx = 0.f, lsy = 0.f;
        #pragma unroll
        for (int i = 0; i < 8; i++) {
            const int j = wave * 8 + i;
            const bf16_t* up = psiu + ((size_t)j * 4032 + b * 63 + t) * 128 + lane * 2;
            const float px = sx[i] + ((float)up[0] - p0x[i]);
            const float py = sy[i] + ((float)up[1] - p0y[i]);
            sx[i] = px * lre[i] - py * lim[i];
            sy[i] = px * lim[i] + py * lre[i];
            lsx += sx[i]; lsy += sy[i];
        }
        red[wave][lane * 2]     = lsx;
        red[wave][lane * 2 + 1] = lsy;
        __syncthreads();
        if (tid < 128) {
            float s = 0.f;
            #pragma unroll
            for (int w = 0; w < 8; w++) s += red[w][tid];
            S[tid] = s;
        }
        __syncthreads();
        if (tid < 16) {
            float acc = 0.f;
            for (int l = 0; l < 128; l++) acc += S[l] * Cs[tid * 128 + l];
            ypred[(b * 63 + t) * 16 + tid] = acc;
        }
        __syncthreads();
    }
}

// ---------------------------------------------------------------------------
extern "C" void kernel_launch(void* const* d_in, const int* in_sizes, int n_in,
                              void* d_out, int out_size, void* d_ws, size_t ws_size,
                              hipStream_t stream) {
    const float* xs      = (const float*)d_in[0];
    const float* us      = (const float*)d_in[1];
    const float* x_gamma = (const float*)d_in[2];
    const float* x_beta  = (const float*)d_in[3];
    const float* xW1     = (const float*)d_in[4];
    const float* xb1     = (const float*)d_in[5];
    const float* xW2     = (const float*)d_in[6];
    const float* xb2     = (const float*)d_in[7];
    const float* xW3     = (const float*)d_in[8];
    const float* x_scale = (const float*)d_in[9];
    const float* u_gamma = (const float*)d_in[10];
    const float* u_beta  = (const float*)d_in[11];
    const float* uW1     = (const float*)d_in[12];
    const float* ub1     = (const float*)d_in[13];
    const float* uW2     = (const float*)d_in[14];
    const float* ub2     = (const float*)d_in[15];
    const float* uW3     = (const float*)d_in[16];
    const float* u_scale = (const float*)d_in[17];
    const float* reL     = (const float*)d_in[18];
    const float* imL     = (const float*)d_in[19];
    const float* C_W     = (const float*)d_in[20];

    char* ws = (char*)d_ws;
    size_t off = 0;
    auto alloc = [&](size_t bytes) -> char* {
        char* p = ws + off;
        off += (bytes + 255) & ~(size_t)255;
        return p;
    };
    float*  stats_x = (float*)alloc(64 * 4);
    float*  stats_u = (float*)alloc(64 * 4);
    bf16_t* Xn   = (bf16_t*)alloc((size_t)4096 * 32 * 2);
    bf16_t* Un   = (bf16_t*)alloc((size_t)4032 * 32 * 2);
    bf16_t* xW1t = (bf16_t*)alloc((size_t)64 * 256 * 32 * 2);
    float*  xb1p = (float*) alloc((size_t)64 * 256 * 4);
    bf16_t* xW2t = (bf16_t*)alloc((size_t)64 * 256 * 256 * 2);
    bf16_t* xW3t = (bf16_t*)alloc((size_t)64 * 128 * 256 * 2);
    bf16_t* uW1t = (bf16_t*)alloc((size_t)64 * 256 * 32 * 2);
    float*  ub1p = (float*) alloc((size_t)64 * 256 * 4);
    bf16_t* uW2t = (bf16_t*)alloc((size_t)64 * 256 * 256 * 2);
    bf16_t* uW3t = (bf16_t*)alloc((size_t)64 * 128 * 256 * 2);
    float*  psi0 = (float*) alloc((size_t)64 * 128 * 4);
    bf16_t* phi  = (bf16_t*)alloc((size_t)64 * 4096 * 128 * 2);
    bf16_t* psiu = (bf16_t*)alloc((size_t)64 * 4032 * 128 * 2);

    float* y_out     = (float*)d_out;
    float* ypred_out = y_out + 64 * 63 * 16;

    bn_stats_kernel<<<1, 256, 0, stream>>>(xs, 4096, 16, stats_x);
    bn_stats_kernel<<<1, 256, 0, stream>>>(us, 4032, 8, stats_u);
    normalize_kernel<<<512, 256, 0, stream>>>(xs, stats_x, Xn, 4096, 16);
    normalize_kernel<<<504, 256, 0, stream>>>(us, stats_u, Un, 4032, 8);
    prep_w1_kernel<<<64, 256, 0, stream>>>(xW1, xb1, x_gamma, x_beta, xW1t, xb1p, 16);
    prep_w1_kernel<<<64, 256, 0, stream>>>(uW1, ub1, u_gamma, u_beta, uW1t, ub1p, 8);
    transpose_kernel<<<dim3(8, 8, 64), 256, 0, stream>>>(xW2, xW2t, nullptr, 256, 256);
    transpose_kernel<<<dim3(4, 8, 64), 256, 0, stream>>>(xW3, xW3t, x_scale, 256, 128);
    transpose_kernel<<<dim3(8, 8, 64), 256, 0, stream>>>(uW2, uW2t, nullptr, 256, 256);
    transpose_kernel<<<dim3(4, 8, 64), 256, 0, stream>>>(uW3, uW3t, u_scale, 256, 128);
    psi0_kernel<<<64, 256, 0, stream>>>(ub1p, uW2t, ub2, uW3t, psi0);
    fused_mlp_kernel<<<dim3(64, 64), 256, 0, stream>>>(Xn, xW1t, xb1p, xW2t, xb2, xW3t, phi, 4096);
    fused_mlp_kernel<<<dim3(63, 64), 256, 0, stream>>>(Un, uW1t, ub1p, uW2t, ub2, uW3t, psiu, 4032);
    y_kernel<<<dim3(63, 64), 128, 0, stream>>>(phi, C_W, y_out);
    recur_kernel<<<64, 512, 0, stream>>>(phi, psiu, psi0, reL, imL, C_W, ypred_out);
}